// Round 10
// baseline (171.270 us; speedup 1.0000x reference)
//
#include <hip/hip_runtime.h>
#include <hip/hip_bf16.h>

#define HEADS 8
#define DIM_HEAD 32
#define GROUPS 8
#define CCH 256            // channels
#define NTOK 4096          // d*h*w = 16^3
#define EPS 1e-5f
#define GN_SPLIT 32
#define JS 4               // attention j-split (occupancy)

typedef _Float16 half8 __attribute__((ext_vector_type(8)));
typedef float f32x4 __attribute__((ext_vector_type(4)));

// -------------------- 1a. GroupNorm partial stats --------------------
__global__ void gn_stats_partial(const float* __restrict__ x, float* __restrict__ part) {
    const int g  = blockIdx.y;
    const int sp = blockIdx.x;
    const int M = (CCH / GROUPS) * NTOK;        // 131072 contiguous floats per group
    const int chunk = M / GN_SPLIT;             // 4096
    const float4* p = (const float4*)(x + (size_t)g * M + (size_t)sp * chunk);
    float s = 0.f, ss = 0.f;
    for (int i = threadIdx.x; i < chunk / 4; i += blockDim.x) {
        float4 v = p[i];
        s  += v.x + v.y + v.z + v.w;
        ss += v.x*v.x + v.y*v.y + v.z*v.z + v.w*v.w;
    }
    #pragma unroll
    for (int off = 32; off; off >>= 1) {
        s  += __shfl_down(s,  off);
        ss += __shfl_down(ss, off);
    }
    __shared__ float sh0[8], sh1[8];
    const int wave = threadIdx.x >> 6, lane = threadIdx.x & 63;
    if (lane == 0) { sh0[wave] = s; sh1[wave] = ss; }
    __syncthreads();
    if (threadIdx.x == 0) {
        float S = 0.f, SS = 0.f;
        const int nw = blockDim.x >> 6;
        for (int w = 0; w < nw; ++w) { S += sh0[w]; SS += sh1[w]; }
        part[(g * GN_SPLIT + sp) * 2]     = S;
        part[(g * GN_SPLIT + sp) * 2 + 1] = SS;
    }
}

// -------------------- 1b. GroupNorm finalize --------------------
__global__ void gn_stats_final(const float* __restrict__ part, float* __restrict__ stats) {
    const int g = blockIdx.x;           // 8 blocks, 64 threads
    float s = 0.f, ss = 0.f;
    if (threadIdx.x < GN_SPLIT) {
        s  = part[(g * GN_SPLIT + threadIdx.x) * 2];
        ss = part[(g * GN_SPLIT + threadIdx.x) * 2 + 1];
    }
    #pragma unroll
    for (int off = 16; off; off >>= 1) {
        s  += __shfl_down(s,  off);
        ss += __shfl_down(ss, off);
    }
    if (threadIdx.x == 0) {
        const int M = (CCH / GROUPS) * NTOK;
        const float mean = s / (float)M;
        const float var  = ss / (float)M - mean * mean;
        stats[g * 2]     = mean;
        stats[g * 2 + 1] = rsqrtf(var + EPS);
    }
}

// -------------------- 2. Fold GroupNorm into QKV weights --------------------
__global__ void fold_qkv(const float* __restrict__ w, const float* __restrict__ b,
                         const float* __restrict__ gamma, const float* __restrict__ beta,
                         const float* __restrict__ stats,
                         float* __restrict__ w2, float* __restrict__ b2) {
    const int o = blockIdx.x;           // 0..767
    const int c = threadIdx.x;          // 0..255
    const int g = c >> 5;
    const float mean = stats[g * 2];
    const float rstd = stats[g * 2 + 1];
    const float sc = gamma[c] * rstd;
    const float sh = beta[c] - mean * sc;
    const float wv = w[(size_t)o * CCH + c];
    w2[(size_t)o * CCH + c] = wv * sc;
    float t = wv * sh;
    #pragma unroll
    for (int off = 32; off; off >>= 1) t += __shfl_down(t, off);
    __shared__ float shred[4];
    const int wave = threadIdx.x >> 6, lane = threadIdx.x & 63;
    if (lane == 0) shred[wave] = t;
    __syncthreads();
    if (threadIdx.x == 0)
        b2[o] = b[o] + shred[0] + shred[1] + shred[2] + shred[3];
}

// -------------------- 3. QKV GEMM, software-pipelined, 8 outputs/thread ------
#define QKV_OT 8
__global__ __launch_bounds__(256)
void qkv_gemm(const float* __restrict__ x, const float* __restrict__ w,
              const float* __restrict__ b,
              _Float16* __restrict__ q_h, _Float16* __restrict__ k_h,
              _Float16* __restrict__ vT_h) {
    const int j  = blockIdx.x * blockDim.x + threadIdx.x;  // 0..4095
    const int ob = blockIdx.y * QKV_OT;                    // 0..767 step 8
    float acc[QKV_OT];
    #pragma unroll
    for (int u = 0; u < QKV_OT; ++u) acc[u] = b[ob + u];
    float xc[8], xn[8];
    #pragma unroll
    for (int u = 0; u < 8; ++u) xc[u] = x[(size_t)u * NTOK + j];
    for (int c = 0; c < CCH; c += 8) {
        if (c + 8 < CCH) {
            #pragma unroll
            for (int u = 0; u < 8; ++u) xn[u] = x[(size_t)(c + 8 + u) * NTOK + j];
        }
        #pragma unroll
        for (int v = 0; v < QKV_OT; ++v) {
            const float* wr = w + (size_t)(ob + v) * CCH + c;  // wave-uniform -> s_load
            #pragma unroll
            for (int u = 0; u < 8; ++u)
                acc[v] = fmaf(wr[u], xc[u], acc[v]);
        }
        #pragma unroll
        for (int u = 0; u < 8; ++u) xc[u] = xn[u];
    }
    const int part  = ob >> 8;
    const int h     = (ob & 255) >> 5;
    const int dbase = ob & 31;          // 0, 8, 16, 24
    if (part == 0) {
        const float scale = 0.17677669529663687f;  // 32^-0.5 baked into Q
        __attribute__((aligned(16))) _Float16 hv[QKV_OT];
        #pragma unroll
        for (int u = 0; u < QKV_OT; ++u) hv[u] = (_Float16)(acc[u] * scale);
        *(uint4*)(q_h + ((size_t)h * NTOK + j) * DIM_HEAD + dbase) = *(const uint4*)hv;
    } else if (part == 1) {
        __attribute__((aligned(16))) _Float16 hv[QKV_OT];
        #pragma unroll
        for (int u = 0; u < QKV_OT; ++u) hv[u] = (_Float16)acc[u];
        *(uint4*)(k_h + ((size_t)h * NTOK + j) * DIM_HEAD + dbase) = *(const uint4*)hv;
    } else {
        // V stored transposed: vT[h][d][j]; 2B/lane stores, coalesced in j.
        #pragma unroll
        for (int u = 0; u < QKV_OT; ++u)
            vT_h[((size_t)h * DIM_HEAD + dbase + u) * NTOK + j] = (_Float16)acc[u];
    }
}

// -------------------- 4. Flash attention partial: no K/V staging --------------
// R9 lesson: the kernel is VALU/DS-issue-bound; K,V per (h,chunk) are 64 KB each
// (L2-resident; identical rows re-read by all 4 waves -> L1 hits). Staging them
// in LDS cost 2 barriers + ~10 DS ops/tile and capped residency via 26.6 KB LDS.
// Now K and V fragments load DIRECTLY from global; only the per-wave P tile
// lives in LDS (XOR-swizzled on 16B units -> permutation start-banks, 2 KB/wave,
// no __syncthreads anywhere).
__global__ __launch_bounds__(256)
void attn_mfma(const _Float16* __restrict__ q_h, const _Float16* __restrict__ k_h,
               const _Float16* __restrict__ vT_h,
               float* __restrict__ pm, float* __restrict__ pl,
               float* __restrict__ pacc) {
    const int tid = threadIdx.x;
    const int w = tid >> 6, lane = tid & 63;
    const int la = lane & 15, lg = lane >> 4;
    const int h = blockIdx.y;
    const int s = blockIdx.z;
    const int qbase = blockIdx.x * 64 + w * 16;
    const int jlen = NTOK / JS;          // 1024
    const int j0 = s * jlen;

    // per-wave P tile: 16 q-rows x 64 halves (128 B row stride), XOR-swizzled
    __shared__ __align__(16) _Float16 plds[4][16 * 64];    // 8 KB total

    const half8 aq = *(const half8*)(q_h + ((size_t)h * NTOK + qbase + la) * DIM_HEAD + lg * 8);

    f32x4 acc0 = {0.f, 0.f, 0.f, 0.f};
    f32x4 acc1 = {0.f, 0.f, 0.f, 0.f};
    float m = -1e30f, l = 0.f;           // per-lane: query la

    const _Float16* kg = k_h  + (size_t)h * NTOK * DIM_HEAD + (size_t)j0 * DIM_HEAD;
    const _Float16* vg = vT_h + (size_t)h * DIM_HEAD * NTOK + j0;
    char* pw = (char*)&plds[w][0];

    const int NT = jlen / 64;     // 16
    for (int t = 0; t < NT; ++t) {
        const int jt = t * 64;
        // ---- QK^T swapped, K fragments straight from global (L1/L2-hit) ----
        f32x4 sc[4];
        #pragma unroll
        for (int sub = 0; sub < 4; ++sub) {
            const half8 ak = *(const half8*)(kg + (size_t)(jt + sub * 16 + la) * DIM_HEAD + lg * 8);
            f32x4 z = {0.f, 0.f, 0.f, 0.f};
            sc[sub] = __builtin_amdgcn_mfma_f32_16x16x32_f16(ak, aq, z, 0, 0, 0);
        }
        // ---- per-lane max over 16 regs + 2-shfl cross-group reduce ----
        float tm = fmaxf(fmaxf(sc[0][0], sc[0][1]), fmaxf(sc[0][2], sc[0][3]));
        #pragma unroll
        for (int sub = 1; sub < 4; ++sub) {
            tm = fmaxf(tm, fmaxf(fmaxf(sc[sub][0], sc[sub][1]),
                                 fmaxf(sc[sub][2], sc[sub][3])));
        }
        tm = fmaxf(tm, __shfl_xor(tm, 16));
        tm = fmaxf(tm, __shfl_xor(tm, 32));
        const float mn   = fmaxf(m, tm);
        const float corr = __expf(m - mn);   // for query la
        m = mn;
        l *= corr;
        #pragma unroll
        for (int r = 0; r < 4; ++r) {
            const float cq = __shfl(corr, lg * 4 + r);
            acc0[r] *= cq;
            acc1[r] *= cq;
        }
        // ---- probabilities: 16 exps, packed b64 stores, XOR-swizzled units ----
        float ps = 0.f;
        #pragma unroll
        for (int sub = 0; sub < 4; ++sub) {
            union { _Float16 hp[4]; uint2 u; } pk;
            #pragma unroll
            for (int r = 0; r < 4; ++r) {
                const float p = __expf(sc[sub][r] - mn);
                ps += p;
                pk.hp[r] = (_Float16)p;
            }
            // logical halves [la][sub*16 + lg*4 .. +3]; 16B-unit = sub*2+(lg>>1)
            const int unit = (sub * 2 + (lg >> 1)) ^ (la & 7);
            *(uint2*)(pw + la * 128 + unit * 16 + (lg & 1) * 8) = pk.u;
        }
        l += ps;
        // ---- PV: V^T fragments straight from global; pa via swizzled read ----
        #pragma unroll
        for (int kc = 0; kc < 2; ++kc) {
            const int runit = (kc * 4 + lg) ^ (la & 7);
            const half8 pa = *(const half8*)(pw + la * 128 + runit * 16);
            const half8 v0 = *(const half8*)(vg + (size_t)(la     ) * NTOK + jt + kc * 32 + lg * 8);
            const half8 v1 = *(const half8*)(vg + (size_t)(la + 16) * NTOK + jt + kc * 32 + lg * 8);
            acc0 = __builtin_amdgcn_mfma_f32_16x16x32_f16(pa, v0, acc0, 0, 0, 0);
            acc1 = __builtin_amdgcn_mfma_f32_16x16x32_f16(pa, v1, acc1, 0, 0, 0);
        }
    }
    // ---- epilogue: reduce l across the 4 replicas, store raw partial state ----
    float lt = l;
    lt += __shfl_xor(lt, 16);
    lt += __shfl_xor(lt, 32);
    const size_t pbase = (size_t)(h * JS + s) * NTOK + qbase;
    if (lane < 16) {
        pm[pbase + la] = m;
        pl[pbase + la] = lt;
    }
    #pragma unroll
    for (int r = 0; r < 4; ++r) {
        const size_t pq = pbase + lg * 4 + r;
        pacc[pq * DIM_HEAD + la     ] = acc0[r];
        pacc[pq * DIM_HEAD + la + 16] = acc1[r];
    }
}

// -------------------- 5. Combine partial softmax states (JS=4) --------------------
__global__ void attn_combine4(const float* __restrict__ pm, const float* __restrict__ pl,
                              const float* __restrict__ pacc, float* __restrict__ att) {
    const int i = blockIdx.x * blockDim.x + threadIdx.x;   // 0..4095
    const int h = blockIdx.y;
    float mv[JS], lv[JS];
    float mM = -1e30f;
    #pragma unroll
    for (int s = 0; s < JS; ++s) {
        const size_t pidx = ((size_t)(h * JS + s) * NTOK + i);
        mv[s] = pm[pidx];
        lv[s] = pl[pidx];
        mM = fmaxf(mM, mv[s]);
    }
    float wv[JS];
    float denom = 0.f;
    #pragma unroll
    for (int s = 0; s < JS; ++s) {
        wv[s] = __expf(mv[s] - mM);
        denom += lv[s] * wv[s];
    }
    const float inv = 1.f / denom;
    #pragma unroll
    for (int d0 = 0; d0 < DIM_HEAD; d0 += 4) {
        float o0 = 0.f, o1 = 0.f, o2 = 0.f, o3 = 0.f;
        #pragma unroll
        for (int s = 0; s < JS; ++s) {
            const size_t pidx = ((size_t)(h * JS + s) * NTOK + i);
            float4 a = *(const float4*)(pacc + pidx * DIM_HEAD + d0);
            o0 = fmaf(a.x, wv[s], o0);
            o1 = fmaf(a.y, wv[s], o1);
            o2 = fmaf(a.z, wv[s], o2);
            o3 = fmaf(a.w, wv[s], o3);
        }
        att[(size_t)(h * DIM_HEAD + d0    ) * NTOK + i] = o0 * inv;
        att[(size_t)(h * DIM_HEAD + d0 + 1) * NTOK + i] = o1 * inv;
        att[(size_t)(h * DIM_HEAD + d0 + 2) * NTOK + i] = o2 * inv;
        att[(size_t)(h * DIM_HEAD + d0 + 3) * NTOK + i] = o3 * inv;
    }
}

// -------------------- 6. Output projection, software-pipelined, 4 outputs/thread --
#define OUT_OT 4
__global__ __launch_bounds__(256)
void out_proj(const float* __restrict__ att, const float* __restrict__ w,
              const float* __restrict__ b, const float* __restrict__ x,
              float* __restrict__ out) {
    const int j  = blockIdx.x * blockDim.x + threadIdx.x;  // 0..4095
    const int ob = blockIdx.y * OUT_OT;                    // 0..255 step 4
    float acc[OUT_OT];
    #pragma unroll
    for (int u = 0; u < OUT_OT; ++u) acc[u] = b[ob + u];
    float ac[8], an[8];
    #pragma unroll
    for (int u = 0; u < 8; ++u) ac[u] = att[(size_t)u * NTOK + j];
    for (int c = 0; c < CCH; c += 8) {
        if (c + 8 < CCH) {
            #pragma unroll
            for (int u = 0; u < 8; ++u) an[u] = att[(size_t)(c + 8 + u) * NTOK + j];
        }
        #pragma unroll
        for (int v = 0; v < OUT_OT; ++v) {
            const float* wr = w + (size_t)(ob + v) * CCH + c;  // wave-uniform -> s_load
            #pragma unroll
            for (int u = 0; u < 8; ++u)
                acc[v] = fmaf(wr[u], ac[u], acc[v]);
        }
        #pragma unroll
        for (int u = 0; u < 8; ++u) ac[u] = an[u];
    }
    #pragma unroll
    for (int u = 0; u < OUT_OT; ++u) {
        const size_t idx = (size_t)(ob + u) * NTOK + j;
        out[idx] = acc[u] + x[idx];
    }
}

extern "C" void kernel_launch(void* const* d_in, const int* in_sizes, int n_in,
                              void* d_out, int out_size, void* d_ws, size_t ws_size,
                              hipStream_t stream) {
    const float* x     = (const float*)d_in[0];
    const float* gamma = (const float*)d_in[1];
    const float* beta  = (const float*)d_in[2];
    const float* w_qkv = (const float*)d_in[3];
    const float* b_qkv = (const float*)d_in[4];
    const float* w_out = (const float*)d_in[5];
    const float* b_out = (const float*)d_in[6];
    float* out = (float*)d_out;

    float* ws    = (float*)d_ws;
    float* stats = ws;                          // 64
    float* part  = stats + 64;                  // 512
    float* w2    = part  + 512;                 // 768*256 = 196608
    float* b2    = w2    + 196608;              // 768
    float* att   = b2    + 768;                 // 256*4096 = 1048576 (fp32)
    float* pm    = att   + 1048576;             // 8*4*4096 = 131072
    float* pl    = pm    + 131072;              // 131072
    float* pacc  = pl    + 131072;              // 8*4*4096*32 = 4194304 (16 MB)
    _Float16* q_h  = (_Float16*)(pacc + 4194304);          // 8*4096*32 halves (2MB)
    _Float16* k_h  = q_h + (size_t)HEADS * NTOK * DIM_HEAD;
    _Float16* vT_h = k_h + (size_t)HEADS * NTOK * DIM_HEAD;
    // total ~34 MB (ws proven >= 92 MB in round 2)

    {
        dim3 g(GN_SPLIT, GROUPS);
        gn_stats_partial<<<g, 256, 0, stream>>>(x, part);
    }
    gn_stats_final<<<GROUPS, 64, 0, stream>>>(part, stats);
    fold_qkv<<<3 * CCH, 256, 0, stream>>>(w_qkv, b_qkv, gamma, beta, stats, w2, b2);
    {
        dim3 g(NTOK / 256, 3 * CCH / QKV_OT);
        qkv_gemm<<<g, 256, 0, stream>>>(x, w2, b2, q_h, k_h, vT_h);
    }
    {
        dim3 g(NTOK / 64, HEADS, JS);
        attn_mfma<<<g, 256, 0, stream>>>(q_h, k_h, vT_h, pm, pl, pacc);
    }
    {
        dim3 g(NTOK / 256, HEADS);
        attn_combine4<<<g, 256, 0, stream>>>(pm, pl, pacc, att);
    }
    {
        dim3 g(NTOK / 256, CCH / OUT_OT);
        out_proj<<<g, 256, 0, stream>>>(att, w_out, b_out, x, out);
    }
}

// Round 11
// 171.210 us; speedup vs baseline: 1.0004x; 1.0004x over previous
//
#include <hip/hip_runtime.h>
#include <hip/hip_bf16.h>

#define HEADS 8
#define DIM_HEAD 32
#define GROUPS 8
#define CCH 256            // channels
#define NTOK 4096          // d*h*w = 16^3
#define EPS 1e-5f
#define GN_SPLIT 32
#define JS 4               // attention j-split (occupancy)

typedef _Float16 half8 __attribute__((ext_vector_type(8)));
typedef float f32x4 __attribute__((ext_vector_type(4)));

// -------------------- 1a. GroupNorm partial stats --------------------
__global__ void gn_stats_partial(const float* __restrict__ x, float* __restrict__ part) {
    const int g  = blockIdx.y;
    const int sp = blockIdx.x;
    const int M = (CCH / GROUPS) * NTOK;        // 131072 contiguous floats per group
    const int chunk = M / GN_SPLIT;             // 4096
    const float4* p = (const float4*)(x + (size_t)g * M + (size_t)sp * chunk);
    float s = 0.f, ss = 0.f;
    for (int i = threadIdx.x; i < chunk / 4; i += blockDim.x) {
        float4 v = p[i];
        s  += v.x + v.y + v.z + v.w;
        ss += v.x*v.x + v.y*v.y + v.z*v.z + v.w*v.w;
    }
    #pragma unroll
    for (int off = 32; off; off >>= 1) {
        s  += __shfl_down(s,  off);
        ss += __shfl_down(ss, off);
    }
    __shared__ float sh0[8], sh1[8];
    const int wave = threadIdx.x >> 6, lane = threadIdx.x & 63;
    if (lane == 0) { sh0[wave] = s; sh1[wave] = ss; }
    __syncthreads();
    if (threadIdx.x == 0) {
        float S = 0.f, SS = 0.f;
        const int nw = blockDim.x >> 6;
        for (int w = 0; w < nw; ++w) { S += sh0[w]; SS += sh1[w]; }
        part[(g * GN_SPLIT + sp) * 2]     = S;
        part[(g * GN_SPLIT + sp) * 2 + 1] = SS;
    }
}

// -------------------- 1b. GroupNorm finalize --------------------
__global__ void gn_stats_final(const float* __restrict__ part, float* __restrict__ stats) {
    const int g = blockIdx.x;           // 8 blocks, 64 threads
    float s = 0.f, ss = 0.f;
    if (threadIdx.x < GN_SPLIT) {
        s  = part[(g * GN_SPLIT + threadIdx.x) * 2];
        ss = part[(g * GN_SPLIT + threadIdx.x) * 2 + 1];
    }
    #pragma unroll
    for (int off = 16; off; off >>= 1) {
        s  += __shfl_down(s,  off);
        ss += __shfl_down(ss, off);
    }
    if (threadIdx.x == 0) {
        const int M = (CCH / GROUPS) * NTOK;
        const float mean = s / (float)M;
        const float var  = ss / (float)M - mean * mean;
        stats[g * 2]     = mean;
        stats[g * 2 + 1] = rsqrtf(var + EPS);
    }
}

// -------------------- 2. Fold GroupNorm into QKV weights --------------------
__global__ void fold_qkv(const float* __restrict__ w, const float* __restrict__ b,
                         const float* __restrict__ gamma, const float* __restrict__ beta,
                         const float* __restrict__ stats,
                         float* __restrict__ w2, float* __restrict__ b2) {
    const int o = blockIdx.x;           // 0..767
    const int c = threadIdx.x;          // 0..255
    const int g = c >> 5;
    const float mean = stats[g * 2];
    const float rstd = stats[g * 2 + 1];
    const float sc = gamma[c] * rstd;
    const float sh = beta[c] - mean * sc;
    const float wv = w[(size_t)o * CCH + c];
    w2[(size_t)o * CCH + c] = wv * sc;
    float t = wv * sh;
    #pragma unroll
    for (int off = 32; off; off >>= 1) t += __shfl_down(t, off);
    __shared__ float shred[4];
    const int wave = threadIdx.x >> 6, lane = threadIdx.x & 63;
    if (lane == 0) shred[wave] = t;
    __syncthreads();
    if (threadIdx.x == 0)
        b2[o] = b[o] + shred[0] + shred[1] + shred[2] + shred[3];
}

// -------------------- 3. QKV GEMM, software-pipelined, 8 outputs/thread ------
#define QKV_OT 8
__global__ __launch_bounds__(256)
void qkv_gemm(const float* __restrict__ x, const float* __restrict__ w,
              const float* __restrict__ b,
              _Float16* __restrict__ q_h, _Float16* __restrict__ k_h,
              _Float16* __restrict__ vT_h) {
    const int j  = blockIdx.x * blockDim.x + threadIdx.x;  // 0..4095
    const int ob = blockIdx.y * QKV_OT;                    // 0..767 step 8
    float acc[QKV_OT];
    #pragma unroll
    for (int u = 0; u < QKV_OT; ++u) acc[u] = b[ob + u];
    float xc[8], xn[8];
    #pragma unroll
    for (int u = 0; u < 8; ++u) xc[u] = x[(size_t)u * NTOK + j];
    for (int c = 0; c < CCH; c += 8) {
        if (c + 8 < CCH) {
            #pragma unroll
            for (int u = 0; u < 8; ++u) xn[u] = x[(size_t)(c + 8 + u) * NTOK + j];
        }
        #pragma unroll
        for (int v = 0; v < QKV_OT; ++v) {
            const float* wr = w + (size_t)(ob + v) * CCH + c;  // wave-uniform -> s_load
            #pragma unroll
            for (int u = 0; u < 8; ++u)
                acc[v] = fmaf(wr[u], xc[u], acc[v]);
        }
        #pragma unroll
        for (int u = 0; u < 8; ++u) xc[u] = xn[u];
    }
    const int part  = ob >> 8;
    const int h     = (ob & 255) >> 5;
    const int dbase = ob & 31;          // 0, 8, 16, 24
    if (part == 0) {
        const float scale = 0.17677669529663687f;  // 32^-0.5 baked into Q
        __attribute__((aligned(16))) _Float16 hv[QKV_OT];
        #pragma unroll
        for (int u = 0; u < QKV_OT; ++u) hv[u] = (_Float16)(acc[u] * scale);
        *(uint4*)(q_h + ((size_t)h * NTOK + j) * DIM_HEAD + dbase) = *(const uint4*)hv;
    } else if (part == 1) {
        __attribute__((aligned(16))) _Float16 hv[QKV_OT];
        #pragma unroll
        for (int u = 0; u < QKV_OT; ++u) hv[u] = (_Float16)acc[u];
        *(uint4*)(k_h + ((size_t)h * NTOK + j) * DIM_HEAD + dbase) = *(const uint4*)hv;
    } else {
        // V stored transposed: vT[h][d][j]; 2B/lane stores, coalesced in j.
        #pragma unroll
        for (int u = 0; u < QKV_OT; ++u)
            vT_h[((size_t)h * DIM_HEAD + dbase + u) * NTOK + j] = (_Float16)acc[u];
    }
}

// -------------------- 4. Flash attention partial: direct K/V + reg prefetch ---
// R10 lesson: dropping LDS K/V staging was right (barriers/residency-cap gone)
// but it also dropped the PIPELINE — inline K/V loads put L2 latency on the
// critical path (VALUBusy 65->38%). Restore it in registers: tile t+1's 8 half8
// K/V fragments are issued at the top of tile t's body and drain under ~400cy
// of QK^T+softmax+PV. P tile stays in XOR-swizzled wave-private LDS (8 KB/block,
// no __syncthreads).
__global__ __launch_bounds__(256)
void attn_mfma(const _Float16* __restrict__ q_h, const _Float16* __restrict__ k_h,
               const _Float16* __restrict__ vT_h,
               float* __restrict__ pm, float* __restrict__ pl,
               float* __restrict__ pacc) {
    const int tid = threadIdx.x;
    const int w = tid >> 6, lane = tid & 63;
    const int la = lane & 15, lg = lane >> 4;
    const int h = blockIdx.y;
    const int s = blockIdx.z;
    const int qbase = blockIdx.x * 64 + w * 16;
    const int jlen = NTOK / JS;          // 1024
    const int j0 = s * jlen;

    // per-wave P tile: 16 q-rows x 64 halves (128 B row stride), XOR-swizzled
    __shared__ __align__(16) _Float16 plds[4][16 * 64];    // 8 KB total

    const half8 aq = *(const half8*)(q_h + ((size_t)h * NTOK + qbase + la) * DIM_HEAD + lg * 8);

    f32x4 acc0 = {0.f, 0.f, 0.f, 0.f};
    f32x4 acc1 = {0.f, 0.f, 0.f, 0.f};
    float m = -1e30f, l = 0.f;           // per-lane: query la

    const _Float16* kg = k_h  + (size_t)h * NTOK * DIM_HEAD + (size_t)j0 * DIM_HEAD;
    const _Float16* vg = vT_h + (size_t)h * DIM_HEAD * NTOK + j0;
    char* pw = (char*)&plds[w][0];

    // register double-buffer for K/V fragments (constant indices only)
    half8 kcur[4], vcur[4], knxt[4], vnxt[4];
    #pragma unroll
    for (int sub = 0; sub < 4; ++sub)
        kcur[sub] = *(const half8*)(kg + (size_t)(sub * 16 + la) * DIM_HEAD + lg * 8);
    #pragma unroll
    for (int kc = 0; kc < 2; ++kc) {
        vcur[kc * 2 + 0] = *(const half8*)(vg + (size_t)(la     ) * NTOK + kc * 32 + lg * 8);
        vcur[kc * 2 + 1] = *(const half8*)(vg + (size_t)(la + 16) * NTOK + kc * 32 + lg * 8);
    }

    const int NT = jlen / 64;     // 16
    for (int t = 0; t < NT; ++t) {
        // ---- issue next tile's K/V loads first (drain under this tile's work) ----
        if (t + 1 < NT) {
            const int jn = (t + 1) * 64;
            #pragma unroll
            for (int sub = 0; sub < 4; ++sub)
                knxt[sub] = *(const half8*)(kg + (size_t)(jn + sub * 16 + la) * DIM_HEAD + lg * 8);
            #pragma unroll
            for (int kc = 0; kc < 2; ++kc) {
                vnxt[kc * 2 + 0] = *(const half8*)(vg + (size_t)(la     ) * NTOK + jn + kc * 32 + lg * 8);
                vnxt[kc * 2 + 1] = *(const half8*)(vg + (size_t)(la + 16) * NTOK + jn + kc * 32 + lg * 8);
            }
        }
        // ---- QK^T swapped: sc[sub][r] = S[key=sub*16+lg*4+r][q=la] ----
        f32x4 sc[4];
        #pragma unroll
        for (int sub = 0; sub < 4; ++sub) {
            f32x4 z = {0.f, 0.f, 0.f, 0.f};
            sc[sub] = __builtin_amdgcn_mfma_f32_16x16x32_f16(kcur[sub], aq, z, 0, 0, 0);
        }
        // ---- per-lane max over 16 regs + 2-shfl cross-group reduce ----
        float tm = fmaxf(fmaxf(sc[0][0], sc[0][1]), fmaxf(sc[0][2], sc[0][3]));
        #pragma unroll
        for (int sub = 1; sub < 4; ++sub) {
            tm = fmaxf(tm, fmaxf(fmaxf(sc[sub][0], sc[sub][1]),
                                 fmaxf(sc[sub][2], sc[sub][3])));
        }
        tm = fmaxf(tm, __shfl_xor(tm, 16));
        tm = fmaxf(tm, __shfl_xor(tm, 32));
        const float mn   = fmaxf(m, tm);
        const float corr = __expf(m - mn);   // for query la
        m = mn;
        l *= corr;
        #pragma unroll
        for (int r = 0; r < 4; ++r) {
            const float cq = __shfl(corr, lg * 4 + r);
            acc0[r] *= cq;
            acc1[r] *= cq;
        }
        // ---- probabilities: 16 exps, packed b64 stores, XOR-swizzled units ----
        float ps = 0.f;
        #pragma unroll
        for (int sub = 0; sub < 4; ++sub) {
            union { _Float16 hp[4]; uint2 u; } pk;
            #pragma unroll
            for (int r = 0; r < 4; ++r) {
                const float p = __expf(sc[sub][r] - mn);
                ps += p;
                pk.hp[r] = (_Float16)p;
            }
            // logical halves [la][sub*16 + lg*4 .. +3]; 16B-unit = sub*2+(lg>>1)
            const int unit = (sub * 2 + (lg >> 1)) ^ (la & 7);
            *(uint2*)(pw + la * 128 + unit * 16 + (lg & 1) * 8) = pk.u;
        }
        l += ps;
        // ---- PV with current-tile V fragments; pa via swizzled read ----
        #pragma unroll
        for (int kc = 0; kc < 2; ++kc) {
            const int runit = (kc * 4 + lg) ^ (la & 7);
            const half8 pa = *(const half8*)(pw + la * 128 + runit * 16);
            acc0 = __builtin_amdgcn_mfma_f32_16x16x32_f16(pa, vcur[kc * 2 + 0], acc0, 0, 0, 0);
            acc1 = __builtin_amdgcn_mfma_f32_16x16x32_f16(pa, vcur[kc * 2 + 1], acc1, 0, 0, 0);
        }
        // ---- rotate buffers ----
        #pragma unroll
        for (int u = 0; u < 4; ++u) kcur[u] = knxt[u];
        #pragma unroll
        for (int u = 0; u < 4; ++u) vcur[u] = vnxt[u];
    }
    // ---- epilogue: reduce l across the 4 replicas, store raw partial state ----
    float lt = l;
    lt += __shfl_xor(lt, 16);
    lt += __shfl_xor(lt, 32);
    const size_t pbase = (size_t)(h * JS + s) * NTOK + qbase;
    if (lane < 16) {
        pm[pbase + la] = m;
        pl[pbase + la] = lt;
    }
    #pragma unroll
    for (int r = 0; r < 4; ++r) {
        const size_t pq = pbase + lg * 4 + r;
        pacc[pq * DIM_HEAD + la     ] = acc0[r];
        pacc[pq * DIM_HEAD + la + 16] = acc1[r];
    }
}

// -------------------- 5. Combine partial softmax states (JS=4) --------------------
__global__ void attn_combine4(const float* __restrict__ pm, const float* __restrict__ pl,
                              const float* __restrict__ pacc, float* __restrict__ att) {
    const int i = blockIdx.x * blockDim.x + threadIdx.x;   // 0..4095
    const int h = blockIdx.y;
    float mv[JS], lv[JS];
    float mM = -1e30f;
    #pragma unroll
    for (int s = 0; s < JS; ++s) {
        const size_t pidx = ((size_t)(h * JS + s) * NTOK + i);
        mv[s] = pm[pidx];
        lv[s] = pl[pidx];
        mM = fmaxf(mM, mv[s]);
    }
    float wv[JS];
    float denom = 0.f;
    #pragma unroll
    for (int s = 0; s < JS; ++s) {
        wv[s] = __expf(mv[s] - mM);
        denom += lv[s] * wv[s];
    }
    const float inv = 1.f / denom;
    #pragma unroll
    for (int d0 = 0; d0 < DIM_HEAD; d0 += 4) {
        float o0 = 0.f, o1 = 0.f, o2 = 0.f, o3 = 0.f;
        #pragma unroll
        for (int s = 0; s < JS; ++s) {
            const size_t pidx = ((size_t)(h * JS + s) * NTOK + i);
            float4 a = *(const float4*)(pacc + pidx * DIM_HEAD + d0);
            o0 = fmaf(a.x, wv[s], o0);
            o1 = fmaf(a.y, wv[s], o1);
            o2 = fmaf(a.z, wv[s], o2);
            o3 = fmaf(a.w, wv[s], o3);
        }
        att[(size_t)(h * DIM_HEAD + d0    ) * NTOK + i] = o0 * inv;
        att[(size_t)(h * DIM_HEAD + d0 + 1) * NTOK + i] = o1 * inv;
        att[(size_t)(h * DIM_HEAD + d0 + 2) * NTOK + i] = o2 * inv;
        att[(size_t)(h * DIM_HEAD + d0 + 3) * NTOK + i] = o3 * inv;
    }
}

// -------------------- 6. Output projection, software-pipelined, 4 outputs/thread --
#define OUT_OT 4
__global__ __launch_bounds__(256)
void out_proj(const float* __restrict__ att, const float* __restrict__ w,
              const float* __restrict__ b, const float* __restrict__ x,
              float* __restrict__ out) {
    const int j  = blockIdx.x * blockDim.x + threadIdx.x;  // 0..4095
    const int ob = blockIdx.y * OUT_OT;                    // 0..255 step 4
    float acc[OUT_OT];
    #pragma unroll
    for (int u = 0; u < OUT_OT; ++u) acc[u] = b[ob + u];
    float ac[8], an[8];
    #pragma unroll
    for (int u = 0; u < 8; ++u) ac[u] = att[(size_t)u * NTOK + j];
    for (int c = 0; c < CCH; c += 8) {
        if (c + 8 < CCH) {
            #pragma unroll
            for (int u = 0; u < 8; ++u) an[u] = att[(size_t)(c + 8 + u) * NTOK + j];
        }
        #pragma unroll
        for (int v = 0; v < OUT_OT; ++v) {
            const float* wr = w + (size_t)(ob + v) * CCH + c;  // wave-uniform -> s_load
            #pragma unroll
            for (int u = 0; u < 8; ++u)
                acc[v] = fmaf(wr[u], ac[u], acc[v]);
        }
        #pragma unroll
        for (int u = 0; u < 8; ++u) ac[u] = an[u];
    }
    #pragma unroll
    for (int u = 0; u < OUT_OT; ++u) {
        const size_t idx = (size_t)(ob + u) * NTOK + j;
        out[idx] = acc[u] + x[idx];
    }
}

extern "C" void kernel_launch(void* const* d_in, const int* in_sizes, int n_in,
                              void* d_out, int out_size, void* d_ws, size_t ws_size,
                              hipStream_t stream) {
    const float* x     = (const float*)d_in[0];
    const float* gamma = (const float*)d_in[1];
    const float* beta  = (const float*)d_in[2];
    const float* w_qkv = (const float*)d_in[3];
    const float* b_qkv = (const float*)d_in[4];
    const float* w_out = (const float*)d_in[5];
    const float* b_out = (const float*)d_in[6];
    float* out = (float*)d_out;

    float* ws    = (float*)d_ws;
    float* stats = ws;                          // 64
    float* part  = stats + 64;                  // 512
    float* w2    = part  + 512;                 // 768*256 = 196608
    float* b2    = w2    + 196608;              // 768
    float* att   = b2    + 768;                 // 256*4096 = 1048576 (fp32)
    float* pm    = att   + 1048576;             // 8*4*4096 = 131072
    float* pl    = pm    + 131072;              // 131072
    float* pacc  = pl    + 131072;              // 8*4*4096*32 = 4194304 (16 MB)
    _Float16* q_h  = (_Float16*)(pacc + 4194304);          // 8*4096*32 halves (2MB)
    _Float16* k_h  = q_h + (size_t)HEADS * NTOK * DIM_HEAD;
    _Float16* vT_h = k_h + (size_t)HEADS * NTOK * DIM_HEAD;
    // total ~34 MB (ws proven >= 92 MB in round 2)

    {
        dim3 g(GN_SPLIT, GROUPS);
        gn_stats_partial<<<g, 256, 0, stream>>>(x, part);
    }
    gn_stats_final<<<GROUPS, 64, 0, stream>>>(part, stats);
    fold_qkv<<<3 * CCH, 256, 0, stream>>>(w_qkv, b_qkv, gamma, beta, stats, w2, b2);
    {
        dim3 g(NTOK / 256, 3 * CCH / QKV_OT);
        qkv_gemm<<<g, 256, 0, stream>>>(x, w2, b2, q_h, k_h, vT_h);
    }
    {
        dim3 g(NTOK / 64, HEADS, JS);
        attn_mfma<<<g, 256, 0, stream>>>(q_h, k_h, vT_h, pm, pl, pacc);
    }
    {
        dim3 g(NTOK / 256, HEADS);
        attn_combine4<<<g, 256, 0, stream>>>(pm, pl, pacc, att);
    }
    {
        dim3 g(NTOK / 256, CCH / OUT_OT);
        out_proj<<<g, 256, 0, stream>>>(att, w_out, b_out, x, out);
    }
}

// Round 12
// 128.477 us; speedup vs baseline: 1.3331x; 1.3326x over previous
//
#include <hip/hip_runtime.h>
#include <hip/hip_bf16.h>

#define HEADS 8
#define DIM_HEAD 32
#define GROUPS 8
#define CCH 256            // channels
#define NTOK 4096          // d*h*w = 16^3
#define EPS 1e-5f
#define GN_SPLIT 32
#define JS 4               // attention j-split (occupancy)

typedef _Float16 half8 __attribute__((ext_vector_type(8)));
typedef float f32x4 __attribute__((ext_vector_type(4)));

// -------------------- 1. GroupNorm partial stats --------------------
__global__ void gn_stats_partial(const float* __restrict__ x, float* __restrict__ part) {
    const int g  = blockIdx.y;
    const int sp = blockIdx.x;
    const int M = (CCH / GROUPS) * NTOK;        // 131072 contiguous floats per group
    const int chunk = M / GN_SPLIT;             // 4096
    const float4* p = (const float4*)(x + (size_t)g * M + (size_t)sp * chunk);
    float s = 0.f, ss = 0.f;
    for (int i = threadIdx.x; i < chunk / 4; i += blockDim.x) {
        float4 v = p[i];
        s  += v.x + v.y + v.z + v.w;
        ss += v.x*v.x + v.y*v.y + v.z*v.z + v.w*v.w;
    }
    #pragma unroll
    for (int off = 32; off; off >>= 1) {
        s  += __shfl_down(s,  off);
        ss += __shfl_down(ss, off);
    }
    __shared__ float sh0[8], sh1[8];
    const int wave = threadIdx.x >> 6, lane = threadIdx.x & 63;
    if (lane == 0) { sh0[wave] = s; sh1[wave] = ss; }
    __syncthreads();
    if (threadIdx.x == 0) {
        float S = 0.f, SS = 0.f;
        const int nw = blockDim.x >> 6;
        for (int w = 0; w < nw; ++w) { S += sh0[w]; SS += sh1[w]; }
        part[(g * GN_SPLIT + sp) * 2]     = S;
        part[(g * GN_SPLIT + sp) * 2 + 1] = SS;
    }
}

// -------------------- 2. Fold GroupNorm into QKV weights (stats fused) -------
// Each block re-derives the 8 group stats from the 512 partials (cheap) —
// removes the gn_stats_final launch.
__global__ void fold_qkv(const float* __restrict__ w, const float* __restrict__ b,
                         const float* __restrict__ gamma, const float* __restrict__ beta,
                         const float* __restrict__ part,
                         float* __restrict__ w2, float* __restrict__ b2) {
    const int o = blockIdx.x;           // 0..767
    const int c = threadIdx.x;          // 0..255
    __shared__ float smean[GROUPS], srstd[GROUPS];
    if (c < GROUPS) {
        float s = 0.f, ss = 0.f;
        #pragma unroll
        for (int i = 0; i < GN_SPLIT; ++i) {
            s  += part[(c * GN_SPLIT + i) * 2];
            ss += part[(c * GN_SPLIT + i) * 2 + 1];
        }
        const float M = (float)((CCH / GROUPS) * NTOK);
        const float mean = s / M;
        const float var  = ss / M - mean * mean;
        smean[c] = mean;
        srstd[c] = rsqrtf(var + EPS);
    }
    __syncthreads();
    const int g = c >> 5;
    const float sc = gamma[c] * srstd[g];
    const float sh = beta[c] - smean[g] * sc;
    const float wv = w[(size_t)o * CCH + c];
    w2[(size_t)o * CCH + c] = wv * sc;
    float t = wv * sh;
    #pragma unroll
    for (int off = 32; off; off >>= 1) t += __shfl_down(t, off);
    __shared__ float shred[4];
    const int wave = threadIdx.x >> 6, lane = threadIdx.x & 63;
    if (lane == 0) shred[wave] = t;
    __syncthreads();
    if (threadIdx.x == 0)
        b2[o] = b[o] + shred[0] + shred[1] + shred[2] + shred[3];
}

// -------------------- 3. QKV GEMM, software-pipelined, 8 outputs/thread ------
#define QKV_OT 8
__global__ __launch_bounds__(256)
void qkv_gemm(const float* __restrict__ x, const float* __restrict__ w,
              const float* __restrict__ b,
              _Float16* __restrict__ q_h, _Float16* __restrict__ k_h,
              _Float16* __restrict__ vT_h) {
    const int j  = blockIdx.x * blockDim.x + threadIdx.x;  // 0..4095
    const int ob = blockIdx.y * QKV_OT;                    // 0..767 step 8
    float acc[QKV_OT];
    #pragma unroll
    for (int u = 0; u < QKV_OT; ++u) acc[u] = b[ob + u];
    float xc[8], xn[8];
    #pragma unroll
    for (int u = 0; u < 8; ++u) xc[u] = x[(size_t)u * NTOK + j];
    for (int c = 0; c < CCH; c += 8) {
        if (c + 8 < CCH) {
            #pragma unroll
            for (int u = 0; u < 8; ++u) xn[u] = x[(size_t)(c + 8 + u) * NTOK + j];
        }
        #pragma unroll
        for (int v = 0; v < QKV_OT; ++v) {
            const float* wr = w + (size_t)(ob + v) * CCH + c;  // wave-uniform -> s_load
            #pragma unroll
            for (int u = 0; u < 8; ++u)
                acc[v] = fmaf(wr[u], xc[u], acc[v]);
        }
        #pragma unroll
        for (int u = 0; u < 8; ++u) xc[u] = xn[u];
    }
    const int part  = ob >> 8;
    const int h     = (ob & 255) >> 5;
    const int dbase = ob & 31;          // 0, 8, 16, 24
    if (part == 0) {
        const float scale = 0.17677669529663687f;  // 32^-0.5 baked into Q
        __attribute__((aligned(16))) _Float16 hv[QKV_OT];
        #pragma unroll
        for (int u = 0; u < QKV_OT; ++u) hv[u] = (_Float16)(acc[u] * scale);
        *(uint4*)(q_h + ((size_t)h * NTOK + j) * DIM_HEAD + dbase) = *(const uint4*)hv;
    } else if (part == 1) {
        __attribute__((aligned(16))) _Float16 hv[QKV_OT];
        #pragma unroll
        for (int u = 0; u < QKV_OT; ++u) hv[u] = (_Float16)acc[u];
        *(uint4*)(k_h + ((size_t)h * NTOK + j) * DIM_HEAD + dbase) = *(const uint4*)hv;
    } else {
        // V stored transposed: vT[h][d][j]; 2B/lane stores, coalesced in j.
        #pragma unroll
        for (int u = 0; u < QKV_OT; ++u)
            vT_h[((size_t)h * DIM_HEAD + dbase + u) * NTOK + j] = (_Float16)acc[u];
    }
}

// -------------------- 4. Flash attention partial (R9 structure + swizzled P) --
// R10/R11 lesson: LDS K/V staging with reg prefetch IS the pipeline — direct
// global loads (R10) or reg-dbuf (R11) both put L2 latency on the critical path
// (VALUBusy 65 -> 38/44%). Reinstated R9 verbatim, except the P tile: VPAD
// padding -> XOR-swizzled 16B units (verified bit-identical in R10/R11),
// targeting R9's 7.3M bank-conflict cycles.
#define TJ 64
#define VPAD 72     // V^T LDS row stride in halves
__global__ __launch_bounds__(256)
void attn_mfma(const _Float16* __restrict__ q_h, const _Float16* __restrict__ k_h,
               const _Float16* __restrict__ vT_h,
               float* __restrict__ pm, float* __restrict__ pl,
               float* __restrict__ pacc) {
    const int tid = threadIdx.x;
    const int w = tid >> 6, lane = tid & 63;
    const int la = lane & 15, lg = lane >> 4;
    const int h = blockIdx.y;
    const int s = blockIdx.z;
    const int qbase = blockIdx.x * 64 + w * 16;
    const int jlen = NTOK / JS;          // 1024
    const int j0 = s * jlen;

    __shared__ _Float16 lk [2][TJ * DIM_HEAD];             // K tile (2 x 4 KB)
    __shared__ _Float16 lvt[2][DIM_HEAD * VPAD];           // V^T tile (2 x 4.5 KB)
    __shared__ __align__(16) _Float16 plds[4][16 * 64];    // per-wave P, swizzled (8 KB)

    const half8 aq = *(const half8*)(q_h + ((size_t)h * NTOK + qbase + la) * DIM_HEAD + lg * 8);

    f32x4 acc0 = {0.f, 0.f, 0.f, 0.f};
    f32x4 acc1 = {0.f, 0.f, 0.f, 0.f};
    float m = -1e30f, l = 0.f;           // per-lane: query la

    const _Float16* kg = k_h  + (size_t)h * NTOK * DIM_HEAD + (size_t)j0 * DIM_HEAD;
    const _Float16* vg = vT_h + (size_t)h * DIM_HEAD * NTOK + j0;
    const int vrow = tid >> 3, vseg = tid & 7;       // V^T staging coords
    char* pw = (char*)&plds[w][0];

    uint4 kreg, vreg;
    kreg = ((const uint4*)kg)[tid];
    vreg = *(const uint4*)(vg + (size_t)vrow * NTOK + vseg * 8);
    ((uint4*)lk[0])[tid] = kreg;
    *(uint4*)&lvt[0][vrow * VPAD + vseg * 8] = vreg;
    kreg = ((const uint4*)(kg + (size_t)TJ * DIM_HEAD))[tid];
    vreg = *(const uint4*)(vg + (size_t)vrow * NTOK + TJ + vseg * 8);
    __syncthreads();

    const int NT = jlen / TJ;     // 16
    for (int t = 0; t < NT; ++t) {
        const int cur = t & 1;
        if (t + 1 < NT) {
            ((uint4*)lk[cur ^ 1])[tid] = kreg;
            *(uint4*)&lvt[cur ^ 1][vrow * VPAD + vseg * 8] = vreg;
            if (t + 2 < NT) {
                kreg = ((const uint4*)(kg + (size_t)(t + 2) * TJ * DIM_HEAD))[tid];
                vreg = *(const uint4*)(vg + (size_t)vrow * NTOK + (t + 2) * TJ + vseg * 8);
            }
        }
        // ---- QK^T swapped: sc[sub][r] = S[key=sub*16+lg*4+r][q=la] ----
        f32x4 sc[4];
        #pragma unroll
        for (int sub = 0; sub < 4; ++sub) {
            const half8 ak = *(const half8*)&lk[cur][(sub * 16 + la) * DIM_HEAD + lg * 8];
            f32x4 z = {0.f, 0.f, 0.f, 0.f};
            sc[sub] = __builtin_amdgcn_mfma_f32_16x16x32_f16(ak, aq, z, 0, 0, 0);
        }
        // ---- per-lane max over 16 regs + 2-shfl cross-group reduce ----
        float tm = fmaxf(fmaxf(sc[0][0], sc[0][1]), fmaxf(sc[0][2], sc[0][3]));
        #pragma unroll
        for (int sub = 1; sub < 4; ++sub) {
            tm = fmaxf(tm, fmaxf(fmaxf(sc[sub][0], sc[sub][1]),
                                 fmaxf(sc[sub][2], sc[sub][3])));
        }
        tm = fmaxf(tm, __shfl_xor(tm, 16));
        tm = fmaxf(tm, __shfl_xor(tm, 32));
        const float mn   = fmaxf(m, tm);
        const float corr = __expf(m - mn);   // for query la
        m = mn;
        l *= corr;
        #pragma unroll
        for (int r = 0; r < 4; ++r) {
            const float cq = __shfl(corr, lg * 4 + r);
            acc0[r] *= cq;
            acc1[r] *= cq;
        }
        // ---- probabilities: 16 exps, packed b64 stores, XOR-swizzled units ----
        float ps = 0.f;
        #pragma unroll
        for (int sub = 0; sub < 4; ++sub) {
            union { _Float16 hp[4]; uint2 u; } pk;
            #pragma unroll
            for (int r = 0; r < 4; ++r) {
                const float p = __expf(sc[sub][r] - mn);
                ps += p;
                pk.hp[r] = (_Float16)p;
            }
            // logical halves [la][sub*16 + lg*4 .. +3]; 16B-unit = sub*2+(lg>>1)
            const int unit = (sub * 2 + (lg >> 1)) ^ (la & 7);
            *(uint2*)(pw + la * 128 + unit * 16 + (lg & 1) * 8) = pk.u;
        }
        l += ps;
        // ---- PV: out[16q][32d] += P[16q][64k] * V[64k][32d] ----
        #pragma unroll
        for (int kc = 0; kc < 2; ++kc) {
            const int runit = (kc * 4 + lg) ^ (la & 7);
            const half8 pa = *(const half8*)(pw + la * 128 + runit * 16);
            const half8 v0 = *(const half8*)&lvt[cur][(la     ) * VPAD + kc * 32 + lg * 8];
            const half8 v1 = *(const half8*)&lvt[cur][(la + 16) * VPAD + kc * 32 + lg * 8];
            acc0 = __builtin_amdgcn_mfma_f32_16x16x32_f16(pa, v0, acc0, 0, 0, 0);
            acc1 = __builtin_amdgcn_mfma_f32_16x16x32_f16(pa, v1, acc1, 0, 0, 0);
        }
        __syncthreads();
    }
    // ---- epilogue: reduce l across the 4 replicas, store raw partial state ----
    float lt = l;
    lt += __shfl_xor(lt, 16);
    lt += __shfl_xor(lt, 32);
    const size_t pbase = (size_t)(h * JS + s) * NTOK + qbase;
    if (lane < 16) {
        pm[pbase + la] = m;
        pl[pbase + la] = lt;
    }
    #pragma unroll
    for (int r = 0; r < 4; ++r) {
        const size_t pq = pbase + lg * 4 + r;
        pacc[pq * DIM_HEAD + la     ] = acc0[r];
        pacc[pq * DIM_HEAD + la + 16] = acc1[r];
    }
}

// -------------------- 5. Combine partial softmax states (JS=4) --------------------
__global__ void attn_combine4(const float* __restrict__ pm, const float* __restrict__ pl,
                              const float* __restrict__ pacc, float* __restrict__ att) {
    const int i = blockIdx.x * blockDim.x + threadIdx.x;   // 0..4095
    const int h = blockIdx.y;
    float mv[JS], lv[JS];
    float mM = -1e30f;
    #pragma unroll
    for (int s = 0; s < JS; ++s) {
        const size_t pidx = ((size_t)(h * JS + s) * NTOK + i);
        mv[s] = pm[pidx];
        lv[s] = pl[pidx];
        mM = fmaxf(mM, mv[s]);
    }
    float wv[JS];
    float denom = 0.f;
    #pragma unroll
    for (int s = 0; s < JS; ++s) {
        wv[s] = __expf(mv[s] - mM);
        denom += lv[s] * wv[s];
    }
    const float inv = 1.f / denom;
    #pragma unroll
    for (int d0 = 0; d0 < DIM_HEAD; d0 += 4) {
        float o0 = 0.f, o1 = 0.f, o2 = 0.f, o3 = 0.f;
        #pragma unroll
        for (int s = 0; s < JS; ++s) {
            const size_t pidx = ((size_t)(h * JS + s) * NTOK + i);
            float4 a = *(const float4*)(pacc + pidx * DIM_HEAD + d0);
            o0 = fmaf(a.x, wv[s], o0);
            o1 = fmaf(a.y, wv[s], o1);
            o2 = fmaf(a.z, wv[s], o2);
            o3 = fmaf(a.w, wv[s], o3);
        }
        att[(size_t)(h * DIM_HEAD + d0    ) * NTOK + i] = o0 * inv;
        att[(size_t)(h * DIM_HEAD + d0 + 1) * NTOK + i] = o1 * inv;
        att[(size_t)(h * DIM_HEAD + d0 + 2) * NTOK + i] = o2 * inv;
        att[(size_t)(h * DIM_HEAD + d0 + 3) * NTOK + i] = o3 * inv;
    }
}

// -------------------- 6. Output projection, software-pipelined, 4 outputs/thread --
#define OUT_OT 4
__global__ __launch_bounds__(256)
void out_proj(const float* __restrict__ att, const float* __restrict__ w,
              const float* __restrict__ b, const float* __restrict__ x,
              float* __restrict__ out) {
    const int j  = blockIdx.x * blockDim.x + threadIdx.x;  // 0..4095
    const int ob = blockIdx.y * OUT_OT;                    // 0..255 step 4
    float acc[OUT_OT];
    #pragma unroll
    for (int u = 0; u < OUT_OT; ++u) acc[u] = b[ob + u];
    float ac[8], an[8];
    #pragma unroll
    for (int u = 0; u < 8; ++u) ac[u] = att[(size_t)u * NTOK + j];
    for (int c = 0; c < CCH; c += 8) {
        if (c + 8 < CCH) {
            #pragma unroll
            for (int u = 0; u < 8; ++u) an[u] = att[(size_t)(c + 8 + u) * NTOK + j];
        }
        #pragma unroll
        for (int v = 0; v < OUT_OT; ++v) {
            const float* wr = w + (size_t)(ob + v) * CCH + c;  // wave-uniform -> s_load
            #pragma unroll
            for (int u = 0; u < 8; ++u)
                acc[v] = fmaf(wr[u], ac[u], acc[v]);
        }
        #pragma unroll
        for (int u = 0; u < 8; ++u) ac[u] = an[u];
    }
    #pragma unroll
    for (int u = 0; u < OUT_OT; ++u) {
        const size_t idx = (size_t)(ob + u) * NTOK + j;
        out[idx] = acc[u] + x[idx];
    }
}

extern "C" void kernel_launch(void* const* d_in, const int* in_sizes, int n_in,
                              void* d_out, int out_size, void* d_ws, size_t ws_size,
                              hipStream_t stream) {
    const float* x     = (const float*)d_in[0];
    const float* gamma = (const float*)d_in[1];
    const float* beta  = (const float*)d_in[2];
    const float* w_qkv = (const float*)d_in[3];
    const float* b_qkv = (const float*)d_in[4];
    const float* w_out = (const float*)d_in[5];
    const float* b_out = (const float*)d_in[6];
    float* out = (float*)d_out;

    float* ws    = (float*)d_ws;
    float* stats = ws;                          // 64 (unused, layout keep)
    float* part  = stats + 64;                  // 512
    float* w2    = part  + 512;                 // 768*256 = 196608
    float* b2    = w2    + 196608;              // 768
    float* att   = b2    + 768;                 // 256*4096 = 1048576 (fp32)
    float* pm    = att   + 1048576;             // 8*4*4096 = 131072
    float* pl    = pm    + 131072;              // 131072
    float* pacc  = pl    + 131072;              // 8*4*4096*32 = 4194304 (16 MB)
    _Float16* q_h  = (_Float16*)(pacc + 4194304);          // 8*4096*32 halves (2MB)
    _Float16* k_h  = q_h + (size_t)HEADS * NTOK * DIM_HEAD;
    _Float16* vT_h = k_h + (size_t)HEADS * NTOK * DIM_HEAD;
    // total ~34 MB (ws proven >= 92 MB in round 2)

    {
        dim3 g(GN_SPLIT, GROUPS);
        gn_stats_partial<<<g, 256, 0, stream>>>(x, part);
    }
    fold_qkv<<<3 * CCH, 256, 0, stream>>>(w_qkv, b_qkv, gamma, beta, part, w2, b2);
    {
        dim3 g(NTOK / 256, 3 * CCH / QKV_OT);
        qkv_gemm<<<g, 256, 0, stream>>>(x, w2, b2, q_h, k_h, vT_h);
    }
    {
        dim3 g(NTOK / 64, HEADS, JS);
        attn_mfma<<<g, 256, 0, stream>>>(q_h, k_h, vT_h, pm, pl, pacc);
    }
    {
        dim3 g(NTOK / 256, HEADS);
        attn_combine4<<<g, 256, 0, stream>>>(pm, pl, pacc, att);
    }
    {
        dim3 g(NTOK / 256, CCH / OUT_OT);
        out_proj<<<g, 256, 0, stream>>>(att, w_out, b_out, x, out);
    }
}

// Round 13
// 106.069 us; speedup vs baseline: 1.6147x; 1.2113x over previous
//
#include <hip/hip_runtime.h>
#include <hip/hip_bf16.h>

#define HEADS 8
#define DIM_HEAD 32
#define GROUPS 8
#define CCH 256            // channels
#define NTOK 4096          // d*h*w = 16^3
#define EPS 1e-5f
#define GN_SPLIT 32
#define JS 4               // attention j-split

typedef _Float16 half8 __attribute__((ext_vector_type(8)));
typedef float f32x4 __attribute__((ext_vector_type(4)));

// -------------------- 1. GroupNorm partial stats --------------------
__global__ void gn_stats_partial(const float* __restrict__ x, float* __restrict__ part) {
    const int g  = blockIdx.y;
    const int sp = blockIdx.x;
    const int M = (CCH / GROUPS) * NTOK;        // 131072 contiguous floats per group
    const int chunk = M / GN_SPLIT;             // 4096
    const float4* p = (const float4*)(x + (size_t)g * M + (size_t)sp * chunk);
    float s = 0.f, ss = 0.f;
    for (int i = threadIdx.x; i < chunk / 4; i += blockDim.x) {
        float4 v = p[i];
        s  += v.x + v.y + v.z + v.w;
        ss += v.x*v.x + v.y*v.y + v.z*v.z + v.w*v.w;
    }
    #pragma unroll
    for (int off = 32; off; off >>= 1) {
        s  += __shfl_down(s,  off);
        ss += __shfl_down(ss, off);
    }
    __shared__ float sh0[8], sh1[8];
    const int wave = threadIdx.x >> 6, lane = threadIdx.x & 63;
    if (lane == 0) { sh0[wave] = s; sh1[wave] = ss; }
    __syncthreads();
    if (threadIdx.x == 0) {
        float S = 0.f, SS = 0.f;
        const int nw = blockDim.x >> 6;
        for (int w = 0; w < nw; ++w) { S += sh0[w]; SS += sh1[w]; }
        part[(g * GN_SPLIT + sp) * 2]     = S;
        part[(g * GN_SPLIT + sp) * 2 + 1] = SS;
    }
}

// -------------------- 2. Fold GN into QKV weights (fp16 out) + convert w_out ----
// Blocks 0..767: w2h[o][c] = fp16(w*gamma*rstd), b2[o] = b + sum_c w*shift.
// Blocks 768..1023: wouth row (o-768) = fp16(w_out row).
__global__ void fold_qkv(const float* __restrict__ w, const float* __restrict__ b,
                         const float* __restrict__ gamma, const float* __restrict__ beta,
                         const float* __restrict__ part, const float* __restrict__ w_out,
                         _Float16* __restrict__ w2h, float* __restrict__ b2,
                         _Float16* __restrict__ wouth) {
    const int o = blockIdx.x;
    const int c = threadIdx.x;          // 0..255
    if (o >= 3 * CCH) {
        const int oo = o - 3 * CCH;
        wouth[(size_t)oo * CCH + c] = (_Float16)w_out[(size_t)oo * CCH + c];
        return;
    }
    __shared__ float smean[GROUPS], srstd[GROUPS];
    if (c < GROUPS) {
        float s = 0.f, ss = 0.f;
        #pragma unroll
        for (int i = 0; i < GN_SPLIT; ++i) {
            s  += part[(c * GN_SPLIT + i) * 2];
            ss += part[(c * GN_SPLIT + i) * 2 + 1];
        }
        const float M = (float)((CCH / GROUPS) * NTOK);
        const float mean = s / M;
        const float var  = ss / M - mean * mean;
        smean[c] = mean;
        srstd[c] = rsqrtf(var + EPS);
    }
    __syncthreads();
    const int g = c >> 5;
    const float sc = gamma[c] * srstd[g];
    const float sh = beta[c] - smean[g] * sc;
    const float wv = w[(size_t)o * CCH + c];
    w2h[(size_t)o * CCH + c] = (_Float16)(wv * sc);
    float t = wv * sh;
    #pragma unroll
    for (int off = 32; off; off >>= 1) t += __shfl_down(t, off);
    __shared__ float shred[4];
    const int wave = threadIdx.x >> 6, lane = threadIdx.x & 63;
    if (lane == 0) shred[wave] = t;
    __syncthreads();
    if (threadIdx.x == 0)
        b2[o] = b[o] + shred[0] + shred[1] + shred[2] + shred[3];
}

// -------------------- 3. Transpose x -> fp16 xT[j][c] (k-contiguous token rows) --
__global__ __launch_bounds__(256)
void x_transpose(const float* __restrict__ x, _Float16* __restrict__ xT) {
    __shared__ float tile[64][65];
    const int jb = blockIdx.x * 64;
    const int cb = blockIdx.y * 64;
    const int tj = threadIdx.x & 63, tc = threadIdx.x >> 6;
    #pragma unroll
    for (int cc = 0; cc < 64; cc += 4)
        tile[cc + tc][tj] = x[(size_t)(cb + cc + tc) * NTOK + jb + tj];
    __syncthreads();
    const int wc = threadIdx.x & 63, wj = threadIdx.x >> 6;
    #pragma unroll
    for (int jj = 0; jj < 64; jj += 4)
        xT[(size_t)(jb + jj + wj) * CCH + cb + wc] = (_Float16)tile[wc][jj + wj];
}

// -------------------- 4. QKV GEMM via MFMA ------------------------------------
// Convention (harness-verified by attn R7-R12): mfma(Afrag from U rows, Bfrag from
// V rows) -> D[row=U-row(lg*4+r)][col=V-row(la)]; fragments read row la, k=lg*8..+7.
// Orientation per part so stores are contiguous: q/k put o on D-col (d=la);
// v puts j on D-col.
__global__ __launch_bounds__(256)
void qkv_mfma(const _Float16* __restrict__ w2h, const float* __restrict__ b2,
              const _Float16* __restrict__ xT,
              _Float16* __restrict__ q_h, _Float16* __restrict__ k_h,
              _Float16* __restrict__ vT_h) {
    const int tid = threadIdx.x, w = tid >> 6, lane = tid & 63;
    const int la = lane & 15, lg = lane >> 4;
    const int jb = blockIdx.x * 64 + w * 16;   // wave's 16 tokens
    const int ob = blockIdx.y * 16;            // 16 output rows
    const int part = ob >> 8;
    f32x4 acc = {0.f, 0.f, 0.f, 0.f};
    if (part < 2) {
        // A = xT token rows (D row = j), B = w2h o-rows (D col = o)
        const _Float16* arow = xT  + (size_t)(jb + la) * CCH;
        const _Float16* brow = w2h + (size_t)(ob + la) * CCH;
        #pragma unroll
        for (int kk = 0; kk < CCH; kk += 32) {
            const half8 a = *(const half8*)(arow + kk + lg * 8);
            const half8 b = *(const half8*)(brow + kk + lg * 8);
            acc = __builtin_amdgcn_mfma_f32_16x16x32_f16(a, b, acc, 0, 0, 0);
        }
        const int h = (ob & 255) >> 5, dbase = ob & 31;
        const float bias = b2[ob + la];
        _Float16* dst = (part == 0) ? q_h : k_h;
        const float scl = (part == 0) ? 0.17677669529663687f : 1.0f;
        #pragma unroll
        for (int r = 0; r < 4; ++r) {
            const int j = jb + lg * 4 + r;
            dst[((size_t)h * NTOK + j) * DIM_HEAD + dbase + la] =
                (_Float16)((acc[r] + bias) * scl);
        }
    } else {
        // A = w2h o-rows (D row = o=d), B = xT token rows (D col = j)
        const _Float16* arow = w2h + (size_t)(ob + la) * CCH;
        const _Float16* brow = xT  + (size_t)(jb + la) * CCH;
        #pragma unroll
        for (int kk = 0; kk < CCH; kk += 32) {
            const half8 a = *(const half8*)(arow + kk + lg * 8);
            const half8 b = *(const half8*)(brow + kk + lg * 8);
            acc = __builtin_amdgcn_mfma_f32_16x16x32_f16(a, b, acc, 0, 0, 0);
        }
        const int h = (ob & 255) >> 5, dbase = ob & 31;
        const float4 b4 = *(const float4*)(b2 + ob + lg * 4);
        const float bb[4] = {b4.x, b4.y, b4.z, b4.w};
        #pragma unroll
        for (int r = 0; r < 4; ++r) {
            const int d = dbase + lg * 4 + r;
            vT_h[((size_t)h * DIM_HEAD + d) * NTOK + jb + la] = (_Float16)(acc[r] + bb[r]);
        }
    }
}

// -------------------- 5. Flash attention partial (R12, unchanged) -------------
#define TJ 64
#define VPAD 72
__global__ __launch_bounds__(256)
void attn_mfma(const _Float16* __restrict__ q_h, const _Float16* __restrict__ k_h,
               const _Float16* __restrict__ vT_h,
               float* __restrict__ pm, float* __restrict__ pl,
               float* __restrict__ pacc) {
    const int tid = threadIdx.x;
    const int w = tid >> 6, lane = tid & 63;
    const int la = lane & 15, lg = lane >> 4;
    const int h = blockIdx.y;
    const int s = blockIdx.z;
    const int qbase = blockIdx.x * 64 + w * 16;
    const int jlen = NTOK / JS;          // 1024
    const int j0 = s * jlen;

    __shared__ _Float16 lk [2][TJ * DIM_HEAD];
    __shared__ _Float16 lvt[2][DIM_HEAD * VPAD];
    __shared__ __align__(16) _Float16 plds[4][16 * 64];

    const half8 aq = *(const half8*)(q_h + ((size_t)h * NTOK + qbase + la) * DIM_HEAD + lg * 8);

    f32x4 acc0 = {0.f, 0.f, 0.f, 0.f};
    f32x4 acc1 = {0.f, 0.f, 0.f, 0.f};
    float m = -1e30f, l = 0.f;

    const _Float16* kg = k_h  + (size_t)h * NTOK * DIM_HEAD + (size_t)j0 * DIM_HEAD;
    const _Float16* vg = vT_h + (size_t)h * DIM_HEAD * NTOK + j0;
    const int vrow = tid >> 3, vseg = tid & 7;
    char* pw = (char*)&plds[w][0];

    uint4 kreg, vreg;
    kreg = ((const uint4*)kg)[tid];
    vreg = *(const uint4*)(vg + (size_t)vrow * NTOK + vseg * 8);
    ((uint4*)lk[0])[tid] = kreg;
    *(uint4*)&lvt[0][vrow * VPAD + vseg * 8] = vreg;
    kreg = ((const uint4*)(kg + (size_t)TJ * DIM_HEAD))[tid];
    vreg = *(const uint4*)(vg + (size_t)vrow * NTOK + TJ + vseg * 8);
    __syncthreads();

    const int NT = jlen / TJ;     // 16
    for (int t = 0; t < NT; ++t) {
        const int cur = t & 1;
        if (t + 1 < NT) {
            ((uint4*)lk[cur ^ 1])[tid] = kreg;
            *(uint4*)&lvt[cur ^ 1][vrow * VPAD + vseg * 8] = vreg;
            if (t + 2 < NT) {
                kreg = ((const uint4*)(kg + (size_t)(t + 2) * TJ * DIM_HEAD))[tid];
                vreg = *(const uint4*)(vg + (size_t)vrow * NTOK + (t + 2) * TJ + vseg * 8);
            }
        }
        f32x4 sc[4];
        #pragma unroll
        for (int sub = 0; sub < 4; ++sub) {
            const half8 ak = *(const half8*)&lk[cur][(sub * 16 + la) * DIM_HEAD + lg * 8];
            f32x4 z = {0.f, 0.f, 0.f, 0.f};
            sc[sub] = __builtin_amdgcn_mfma_f32_16x16x32_f16(ak, aq, z, 0, 0, 0);
        }
        float tm = fmaxf(fmaxf(sc[0][0], sc[0][1]), fmaxf(sc[0][2], sc[0][3]));
        #pragma unroll
        for (int sub = 1; sub < 4; ++sub) {
            tm = fmaxf(tm, fmaxf(fmaxf(sc[sub][0], sc[sub][1]),
                                 fmaxf(sc[sub][2], sc[sub][3])));
        }
        tm = fmaxf(tm, __shfl_xor(tm, 16));
        tm = fmaxf(tm, __shfl_xor(tm, 32));
        const float mn   = fmaxf(m, tm);
        const float corr = __expf(m - mn);
        m = mn;
        l *= corr;
        #pragma unroll
        for (int r = 0; r < 4; ++r) {
            const float cq = __shfl(corr, lg * 4 + r);
            acc0[r] *= cq;
            acc1[r] *= cq;
        }
        float ps = 0.f;
        #pragma unroll
        for (int sub = 0; sub < 4; ++sub) {
            union { _Float16 hp[4]; uint2 u; } pk;
            #pragma unroll
            for (int r = 0; r < 4; ++r) {
                const float p = __expf(sc[sub][r] - mn);
                ps += p;
                pk.hp[r] = (_Float16)p;
            }
            const int unit = (sub * 2 + (lg >> 1)) ^ (la & 7);
            *(uint2*)(pw + la * 128 + unit * 16 + (lg & 1) * 8) = pk.u;
        }
        l += ps;
        #pragma unroll
        for (int kc = 0; kc < 2; ++kc) {
            const int runit = (kc * 4 + lg) ^ (la & 7);
            const half8 pa = *(const half8*)(pw + la * 128 + runit * 16);
            const half8 v0 = *(const half8*)&lvt[cur][(la     ) * VPAD + kc * 32 + lg * 8];
            const half8 v1 = *(const half8*)&lvt[cur][(la + 16) * VPAD + kc * 32 + lg * 8];
            acc0 = __builtin_amdgcn_mfma_f32_16x16x32_f16(pa, v0, acc0, 0, 0, 0);
            acc1 = __builtin_amdgcn_mfma_f32_16x16x32_f16(pa, v1, acc1, 0, 0, 0);
        }
        __syncthreads();
    }
    float lt = l;
    lt += __shfl_xor(lt, 16);
    lt += __shfl_xor(lt, 32);
    const size_t pbase = (size_t)(h * JS + s) * NTOK + qbase;
    if (lane < 16) {
        pm[pbase + la] = m;
        pl[pbase + la] = lt;
    }
    #pragma unroll
    for (int r = 0; r < 4; ++r) {
        const size_t pq = pbase + lg * 4 + r;
        pacc[pq * DIM_HEAD + la     ] = acc0[r];
        pacc[pq * DIM_HEAD + la + 16] = acc1[r];
    }
}

// -------------------- 6. Combine partials -> attT fp16 [i][c] ------------------
__global__ void attn_combine4(const float* __restrict__ pm, const float* __restrict__ pl,
                              const float* __restrict__ pacc, _Float16* __restrict__ attT) {
    const int i = blockIdx.x * blockDim.x + threadIdx.x;   // 0..4095
    const int h = blockIdx.y;
    float mv[JS], lv[JS];
    float mM = -1e30f;
    #pragma unroll
    for (int s = 0; s < JS; ++s) {
        const size_t pidx = ((size_t)(h * JS + s) * NTOK + i);
        mv[s] = pm[pidx];
        lv[s] = pl[pidx];
        mM = fmaxf(mM, mv[s]);
    }
    float wv[JS];
    float denom = 0.f;
    #pragma unroll
    for (int s = 0; s < JS; ++s) {
        wv[s] = __expf(mv[s] - mM);
        denom += lv[s] * wv[s];
    }
    const float inv = 1.f / denom;
    __attribute__((aligned(16))) _Float16 hv[DIM_HEAD];
    #pragma unroll
    for (int d0 = 0; d0 < DIM_HEAD; d0 += 4) {
        float o0 = 0.f, o1 = 0.f, o2 = 0.f, o3 = 0.f;
        #pragma unroll
        for (int s = 0; s < JS; ++s) {
            const size_t pidx = ((size_t)(h * JS + s) * NTOK + i);
            float4 a = *(const float4*)(pacc + pidx * DIM_HEAD + d0);
            o0 = fmaf(a.x, wv[s], o0);
            o1 = fmaf(a.y, wv[s], o1);
            o2 = fmaf(a.z, wv[s], o2);
            o3 = fmaf(a.w, wv[s], o3);
        }
        hv[d0]     = (_Float16)(o0 * inv);
        hv[d0 + 1] = (_Float16)(o1 * inv);
        hv[d0 + 2] = (_Float16)(o2 * inv);
        hv[d0 + 3] = (_Float16)(o3 * inv);
    }
    _Float16* dst = attT + (size_t)i * CCH + h * DIM_HEAD;   // 64 B contiguous
    #pragma unroll
    for (int q = 0; q < 4; ++q) ((uint4*)dst)[q] = ((const uint4*)hv)[q];
}

// -------------------- 7. Output projection via MFMA + bias + residual ----------
__global__ __launch_bounds__(256)
void out_mfma(const _Float16* __restrict__ wouth, const float* __restrict__ bo,
              const _Float16* __restrict__ attT, const float* __restrict__ x,
              float* __restrict__ out) {
    const int tid = threadIdx.x, w = tid >> 6, lane = tid & 63;
    const int la = lane & 15, lg = lane >> 4;
    const int jb = blockIdx.x * 64 + w * 16;
    const int ob = blockIdx.y * 16;
    const _Float16* arow = wouth + (size_t)(ob + la) * CCH;   // D row = o
    const _Float16* brow = attT  + (size_t)(jb + la) * CCH;   // D col = j
    f32x4 acc = {0.f, 0.f, 0.f, 0.f};
    #pragma unroll
    for (int kk = 0; kk < CCH; kk += 32) {
        const half8 a = *(const half8*)(arow + kk + lg * 8);
        const half8 b = *(const half8*)(brow + kk + lg * 8);
        acc = __builtin_amdgcn_mfma_f32_16x16x32_f16(a, b, acc, 0, 0, 0);
    }
    const float4 b4 = *(const float4*)(bo + ob + lg * 4);
    const float bb[4] = {b4.x, b4.y, b4.z, b4.w};
    #pragma unroll
    for (int r = 0; r < 4; ++r) {
        const int o = ob + lg * 4 + r;
        const size_t idx = (size_t)o * NTOK + jb + la;
        out[idx] = acc[r] + bb[r] + x[idx];
    }
}

extern "C" void kernel_launch(void* const* d_in, const int* in_sizes, int n_in,
                              void* d_out, int out_size, void* d_ws, size_t ws_size,
                              hipStream_t stream) {
    const float* x     = (const float*)d_in[0];
    const float* gamma = (const float*)d_in[1];
    const float* beta  = (const float*)d_in[2];
    const float* w_qkv = (const float*)d_in[3];
    const float* b_qkv = (const float*)d_in[4];
    const float* w_out = (const float*)d_in[5];
    const float* b_out = (const float*)d_in[6];
    float* out = (float*)d_out;

    float* ws   = (float*)d_ws;
    float* part = ws;                           // 512
    float* b2   = part + 512;                   // 768
    float* pm   = b2 + 768;                     // 131072
    float* pl   = pm + 131072;                  // 131072
    float* pacc = pl + 131072;                  // 4194304 (16 MB)
    float* fend = pacc + 4194304;
    _Float16* q_h   = (_Float16*)fend;          // 1048576 halves each
    _Float16* k_h   = q_h  + 1048576;
    _Float16* vT_h  = k_h  + 1048576;
    _Float16* xT    = vT_h + 1048576;           // 1048576
    _Float16* w2h   = xT   + 1048576;           // 196608
    _Float16* wouth = w2h  + 196608;            // 65536
    _Float16* attT  = wouth + 65536;            // 1048576
    // total ~29 MB (ws proven >= 92 MB in round 2)

    {
        dim3 g(GN_SPLIT, GROUPS);
        gn_stats_partial<<<g, 256, 0, stream>>>(x, part);
    }
    fold_qkv<<<4 * CCH, 256, 0, stream>>>(w_qkv, b_qkv, gamma, beta, part, w_out,
                                          w2h, b2, wouth);
    {
        dim3 g(NTOK / 64, CCH / 64);
        x_transpose<<<g, 256, 0, stream>>>(x, xT);
    }
    {
        dim3 g(NTOK / 64, 3 * CCH / 16);
        qkv_mfma<<<g, 256, 0, stream>>>(w2h, b2, xT, q_h, k_h, vT_h);
    }
    {
        dim3 g(NTOK / 64, HEADS, JS);
        attn_mfma<<<g, 256, 0, stream>>>(q_h, k_h, vT_h, pm, pl, pacc);
    }
    {
        dim3 g(NTOK / 256, HEADS);
        attn_combine4<<<g, 256, 0, stream>>>(pm, pl, pacc, attT);
    }
    {
        dim3 g(NTOK / 64, CCH / 16);
        out_mfma<<<g, 256, 0, stream>>>(wouth, b_out, attT, x, out);
    }
}